// Round 20
// baseline (314.008 us; speedup 1.0000x reference)
//
#include <hip/hip_runtime.h>
#include <math.h>

#define N_NODES 100000
#define IN_DIM  512
#define HID     5
#define HEADS   5
#define C1      25   // HEADS*HID
#define NC      3
#define NEG     0.2f
#define NPB     64   // nodes per block in k_layer1
#define BSH     7    // 128 dsts per bucket
#define NBUCK   ((N_NODES + 127) >> BSH)   // 782
#define NDIG    1024 // padded bucket count (radix digits)
#define NBH2    512  // hist/write blocks (chunking shared by both passes)
#define HTH2    256  // hist/write threads per block
#define BCAP    6144 // bgroup LDS stage capacity (mean 4352, +27 sigma)
#define LSTR    130  // LDS row stride in floats: bank=(2l+j)%32 -> 2-way (free)

typedef float f32x4 __attribute__((ext_vector_type(4)));

// 12-byte per-head chunk of a packed h1p row: [asrc_h | h1[h][0..4]]
struct __attribute__((packed, aligned(4))) H6 { _Float16 a; _Float16 h[5]; };

__device__ __forceinline__ float lrelu(float v) { return v >= 0.f ? v : NEG * v; }

__device__ __forceinline__ void fma4(float acc[C1], f32x4 xv, const float* w) {
#pragma unroll
    for (int j = 0; j < C1; ++j)
        acc[j] = __builtin_fmaf(xv.w, w[3 * C1 + j],
                 __builtin_fmaf(xv.z, w[2 * C1 + j],
                 __builtin_fmaf(xv.y, w[C1 + j],
                 __builtin_fmaf(xv.x, w[j], acc[j]))));
}

// ---- Fused K1: [blocks 0..NG) gemm role | [NG..NG+NBH2) histogram role.
// Gemm role (R12-redux, fixed): 256 thr / 64 nodes; K in 4 chunks of 128.
// Stage: 4 thr/row load 64x128 floats coalesced (512B DRAM runs) into a
// 33.3KB LDS panel (stride 130 -> 2-way bank alias = free). Compute: wave
// w reads its k-quarter via ds_read_b128 (k wave-uniform -> W1 s_load).
// 8 syncs/block, 4 blocks/CU resident -> stage overlaps compute across
// blocks. Cross-wave LDS reduce + fp16 head-chunk epilogue as R19. ----
__global__ void __launch_bounds__(256)
k_gemm_hist(const float* __restrict__ x, const float* __restrict__ W1,
            const float* __restrict__ as1, const float* __restrict__ ad1,
            const int* __restrict__ ei, int E, int TOT, int NG,
            _Float16* __restrict__ h1p, float* __restrict__ adst,
            int* __restrict__ hist) {
    __shared__ float lds[64 * LSTR];   // 33.3 KB; aliased by hist role + reduce
    int b = blockIdx.x;
    int tid = threadIdx.x;
    if (b >= NG) {
        // ---- histogram role ----
        int* lh = (int*)lds;
        int hb = b - NG;
        for (int i = tid; i < NDIG; i += HTH2) lh[i] = 0;
        __syncthreads();
        int chunk = (TOT + NBH2 - 1) / NBH2;
        int e0 = hb * chunk, e1 = min(e0 + chunk, TOT);
        for (int e = e0 + tid; e < e1; e += HTH2) {
            int d = (e < E) ? ei[E + e] : e - E;
            atomicAdd(&lh[d >> BSH], 1);
        }
        __syncthreads();
        for (int i = tid; i < NDIG; i += HTH2) hist[hb * NDIG + i] = lh[i];
        return;
    }
    // ---- gemm role ----
    int w = __builtin_amdgcn_readfirstlane(tid >> 6);   // wave id = k-quarter
    int l = tid & 63;
    int nbase = b * 64;
    int n = nbase + l;
    // staging map: 4 threads per row, 8 f32x4 each
    int rsub = tid >> 2;                 // 0..63
    int j4 = tid & 3;
    int nst = nbase + rsub;
    int nstc = nst < N_NODES ? nst : N_NODES - 1;       // clamp
    const float* xrow = x + (size_t)nstc * IN_DIM;

    float acc[C1];
#pragma unroll
    for (int j = 0; j < C1; ++j) acc[j] = 0.f;

    f32x4 st[8];
#pragma unroll
    for (int q = 0; q < 8; ++q)
        st[q] = *(const f32x4*)(xrow + (j4 + 4 * q) * 4);   // chunk 0

    for (int ck = 0; ck < 4; ++ck) {
        __syncthreads();                 // prev compute done before overwrite
#pragma unroll
        for (int q = 0; q < 8; ++q) {
            float* p = &lds[rsub * LSTR + (j4 + 4 * q) * 4];
            p[0] = st[q].x; p[1] = st[q].y; p[2] = st[q].z; p[3] = st[q].w;
        }
        __syncthreads();
        if (ck < 3) {
#pragma unroll
            for (int q = 0; q < 8; ++q)
                st[q] = *(const f32x4*)(xrow + (ck + 1) * 128 + (j4 + 4 * q) * 4);
        }
        const float* Wb = W1 + (size_t)(ck * 128 + w * 32) * C1;
#pragma unroll
        for (int kk = 0; kk < 8; ++kk) {
            f32x4 xv = *(const f32x4*)(&lds[l * LSTR + w * 32 + kk * 4]);
            fma4(acc, xv, Wb + (size_t)kk * 4 * C1);
        }
    }
    // cross-wave reduce: red[3][64][26] aliases the panel (19.9KB < 33.3KB)
    float* red = lds;
    __syncthreads();
    if (w > 0) {
#pragma unroll
        for (int j = 0; j < C1; ++j) red[((w - 1) * 64 + l) * 26 + j] = acc[j];
    }
    __syncthreads();
    if (w == 0 && n < N_NODES) {
#pragma unroll
        for (int j = 0; j < C1; ++j)
            acc[j] += red[(0 * 64 + l) * 26 + j] + red[(1 * 64 + l) * 26 + j]
                    + red[(2 * 64 + l) * 26 + j];
        _Float16 hb16[32];
#pragma unroll
        for (int h = 0; h < HEADS; ++h) {
            float s = 0.f, d = 0.f;
#pragma unroll
            for (int cc = 0; cc < HID; ++cc) {
                s += acc[h * HID + cc] * as1[h * HID + cc];
                d += acc[h * HID + cc] * ad1[h * HID + cc];
                hb16[6 * h + 1 + cc] = (_Float16)acc[h * HID + cc];
            }
            hb16[6 * h] = (_Float16)s;
            adst[n * HEADS + h] = d;
        }
        hb16[30] = (_Float16)0.f; hb16[31] = (_Float16)0.f;
        float4* h4 = (float4*)(h1p + (size_t)n * 32);   // 64B row
        const float4* src = (const float4*)hb16;
#pragma unroll
        for (int q = 0; q < 4; ++q) h4[q] = src[q];
    }
}

// ---- radix: per-digit scan over the 512 hist blocks ----
__global__ void __launch_bounds__(NBH2)
k_colscan(int* __restrict__ hist, int* __restrict__ bcnt) {
    __shared__ int sh[NBH2];
    int d = blockIdx.x, t = threadIdx.x;
    int v = hist[t * NDIG + d];
    sh[t] = v;
    __syncthreads();
    for (int ofs = 1; ofs < NBH2; ofs <<= 1) {
        int u = (t >= ofs) ? sh[t - ofs] : 0;
        __syncthreads();
        sh[t] += u;
        __syncthreads();
    }
    hist[t * NDIG + d] = sh[t] - v;   // exclusive over blocks
    if (t == NBH2 - 1) bcnt[d] = sh[t];
}

// ---- radix: exclusive scan of 1024 bucket counts ----
__global__ void __launch_bounds__(NDIG)
k_boff(const int* __restrict__ bcnt, int* __restrict__ boff) {
    __shared__ int sh[NDIG];
    int t = threadIdx.x;
    int v = bcnt[t];
    sh[t] = v;
    __syncthreads();
    for (int ofs = 1; ofs < NDIG; ofs <<= 1) {
        int u = (t >= ofs) ? sh[t - ofs] : 0;
        __syncthreads();
        sh[t] += u;
        __syncthreads();
    }
    boff[t] = sh[t] - v;
}

// ---- radix pass 2: write packed edges (LDS cursors; chunking == hist role) ----
__global__ void __launch_bounds__(HTH2)
k_write(const int* __restrict__ ei, int E, int TOT, const int* __restrict__ hist,
        const int* __restrict__ boff, int* __restrict__ pk) {
    __shared__ int lbase[NDIG];
    __shared__ int lcur[NDIG];
    int b = blockIdx.x, tid = threadIdx.x;
    for (int i = tid; i < NDIG; i += HTH2) {
        lbase[i] = boff[i] + hist[b * NDIG + i];
        lcur[i] = 0;
    }
    __syncthreads();
    int chunk = (TOT + NBH2 - 1) / NBH2;
    int e0 = b * chunk, e1 = min(e0 + chunk, TOT);
    for (int e = e0 + tid; e < e1; e += HTH2) {
        int s, d;
        if (e < E) { s = ei[e]; d = ei[E + e]; } else { s = d = e - E; }
        int dg = d >> BSH;
        int r = atomicAdd(&lcur[dg], 1);
        pk[lbase[dg] + r] = s | ((d & 127) << 17);
    }
}

// ---- per-bucket regroup by dst; single global read of pk (LDS stage) ----
__global__ void __launch_bounds__(512)
k_bgroup(const int* __restrict__ boff, const int* __restrict__ bcnt,
         const int* __restrict__ pk, int* __restrict__ off, int* __restrict__ deg,
         int* __restrict__ ssrc) {
    __shared__ int stage[BCAP];        // 24 KB
    __shared__ int cnt[128], pref[128], lcur[128];
    int b = blockIdx.x, tid = threadIdx.x;
    int n0 = b << BSH;
    if (tid < 128) cnt[tid] = 0;
    __syncthreads();
    int r0 = boff[b], total = bcnt[b];
    for (int idx = tid; idx < total; idx += 512) {
        int v = pk[r0 + idx];
        if (idx < BCAP) stage[idx] = v;
        atomicAdd(&cnt[(v >> 17) & 127], 1);
    }
    __syncthreads();
    if (tid < 128) pref[tid] = cnt[tid];
    __syncthreads();
    for (int ofs = 1; ofs < 128; ofs <<= 1) {
        int u = 0;
        if (tid < 128 && tid >= ofs) u = pref[tid - ofs];
        __syncthreads();
        if (tid < 128) pref[tid] += u;
        __syncthreads();
    }
    if (tid < 128) {
        int n = n0 + tid;
        if (n < N_NODES) {
            off[n] = r0 + pref[tid] - cnt[tid];
            deg[n] = cnt[tid];
        }
        lcur[tid] = 0;
    }
    __syncthreads();
    for (int idx = tid; idx < total; idx += 512) {
        int v = (idx < BCAP) ? stage[idx] : pk[r0 + idx];
        int dl = (v >> 17) & 127;
        int r = atomicAdd(&lcur[dl], 1);
        ssrc[r0 + pref[dl] - cnt[dl] + r] = v & 0x1FFFF;
    }
}

// ---- Layer 1: per-(dst,head) segment softmax (no max-shift).
// ONE dwordx3 load per edge per thread (12B head-chunk). ----
__global__ void __launch_bounds__(NPB * HEADS)
k_layer1(const int* __restrict__ off, const int* __restrict__ deg, const int* __restrict__ ssrc,
         const _Float16* __restrict__ h1p, const float* __restrict__ adst,
         const float* __restrict__ b1, const float* __restrict__ W2,
         const float* __restrict__ as2, const float* __restrict__ ad2,
         float4* __restrict__ n2, float* __restrict__ a2d) {
    __shared__ float sh[NPB * C1];
    int tid = threadIdx.x;            // 0..319
    int ln = tid / HEADS, h = tid % HEADS;
    int n = blockIdx.x * NPB + ln;
    if (n < N_NODES) {
        int st = off[n], cnt = deg[n];
        float adn = adst[n * HEADS + h];
        float den = 0.f;
        float num[HID] = {0.f, 0.f, 0.f, 0.f, 0.f};
        const H6* hp = (const H6*)(h1p) + h;   // chunk h; row stride = 32 halfs
        for (int i = 0; i < cnt; ++i) {
            int s = ssrc[st + i];
            H6 hv = *(const H6*)((const _Float16*)hp + (size_t)s * 32);
            float p = __expf(lrelu((float)hv.a + adn));
            den += p;
#pragma unroll
            for (int c = 0; c < HID; ++c) num[c] = __builtin_fmaf(p, (float)hv.h[c], num[c]);
        }
        float inv = 1.f / den;
#pragma unroll
        for (int c = 0; c < HID; ++c) {
            float v = num[c] * inv + b1[h * HID + c];
            sh[ln * C1 + h * HID + c] = v > 0.f ? v : expm1f(v);
        }
    }
    __syncthreads();
    if (tid < NPB) {
        int nn = blockIdx.x * NPB + tid;
        if (nn < N_NODES) {
            float gg[NC] = {0.f, 0.f, 0.f};
#pragma unroll
            for (int j = 0; j < C1; ++j) {
                float hv = sh[tid * C1 + j];
#pragma unroll
                for (int c = 0; c < NC; ++c) gg[c] += hv * W2[j * NC + c];
            }
            float ssv = 0.f, ddv = 0.f;
#pragma unroll
            for (int c = 0; c < NC; ++c) { ssv += gg[c] * as2[c]; ddv += gg[c] * ad2[c]; }
            n2[nn] = make_float4(ssv, gg[0], gg[1], gg[2]);  // [a2s | g0 g1 g2]
            a2d[nn] = ddv;
        }
    }
}

// ---- Layer 2: per-dst segment softmax (no max-shift) + log_sigmoid ----
__global__ void k_layer2(const int* __restrict__ off, const int* __restrict__ deg,
                         const int* __restrict__ ssrc, const float4* __restrict__ n2,
                         const float* __restrict__ a2d, const float* __restrict__ b2,
                         float* __restrict__ out) {
    int n = blockIdx.x * blockDim.x + threadIdx.x;
    if (n >= N_NODES) return;
    int st = off[n], cnt = deg[n];
    float adn = a2d[n];
    float den = 0.f, num0 = 0.f, num1 = 0.f, num2 = 0.f;
    for (int i = 0; i < cnt; ++i) {
        int s = ssrc[st + i];
        float4 gv = n2[s];
        float p = __expf(lrelu(gv.x + adn));
        den += p;
        num0 = __builtin_fmaf(p, gv.y, num0);
        num1 = __builtin_fmaf(p, gv.z, num1);
        num2 = __builtin_fmaf(p, gv.w, num2);
    }
    float inv = 1.f / den;
    float vv[NC] = {num0 * inv + b2[0], num1 * inv + b2[1], num2 * inv + b2[2]};
#pragma unroll
    for (int c = 0; c < NC; ++c) {
        float v = vv[c];
        out[n * NC + c] = (v >= 0.f) ? -log1pf(__expf(-v)) : v - log1pf(__expf(v));
    }
}

extern "C" void kernel_launch(void* const* d_in, const int* in_sizes, int n_in,
                              void* d_out, int out_size, void* d_ws, size_t ws_size,
                              hipStream_t stream) {
    const float* x   = (const float*)d_in[0];
    const int*   ei  = (const int*)d_in[1];
    const float* W1  = (const float*)d_in[2];
    const float* as1 = (const float*)d_in[3];
    const float* ad1 = (const float*)d_in[4];
    const float* b1  = (const float*)d_in[5];
    const float* W2  = (const float*)d_in[6];
    const float* as2 = (const float*)d_in[7];
    const float* ad2 = (const float*)d_in[8];
    const float* b2  = (const float*)d_in[9];
    float* out = (float*)d_out;
    int E = in_sizes[1] / 2;
    int TOT = E + N_NODES;

    int*   iws = (int*)d_ws;
    float* fws = (float*)d_ws;
    // ints (no memset needed: every word written before read; no overlays)
    int* hist = iws;                       // NBH2*NDIG = 524,288
    int* bcnt = iws + 524288;              // 1024
    int* boff = iws + 525312;              // 1024
    int* off  = iws + 526336;              // N
    int* deg  = iws + 626336;              // N
    int* pk   = iws + 726336;              // TOT
    int* ssrc = pk + TOT;                  // TOT
    size_t fbase = 726336 + 2 * (size_t)TOT;   // ~7.33M floats
    _Float16* h1p = (_Float16*)(fws + fbase);  // N*32 halfs = N*16 floats
    float*  adst = fws + fbase + 1600000;  // N*5
    float4* n2   = (float4*)(fws + fbase + 2100000); // N float4
    float*  a2d  = fws + fbase + 2500000;  // N  (end fbase+2.6M ~ 39.7 MB)

    dim3 blk(256);
    int NB1 = (N_NODES + 255) / 256;  // 391
    int NG  = (N_NODES + 63) / 64;    // 1563 gemm blocks
    k_gemm_hist<<<dim3(NG + NBH2), dim3(256), 0, stream>>>(
        x, W1, as1, ad1, ei, E, TOT, NG, h1p, adst, hist);
    k_colscan<<<dim3(NDIG), dim3(NBH2), 0, stream>>>(hist, bcnt);
    k_boff<<<dim3(1), dim3(NDIG), 0, stream>>>(bcnt, boff);
    k_write<<<dim3(NBH2), dim3(HTH2), 0, stream>>>(ei, E, TOT, hist, boff, pk);
    k_bgroup<<<dim3(NBUCK), dim3(512), 0, stream>>>(boff, bcnt, pk, off, deg, ssrc);
    k_layer1<<<dim3((N_NODES + NPB - 1) / NPB), dim3(NPB * HEADS), 0, stream>>>(
        off, deg, ssrc, h1p, adst, b1, W2, as2, ad2, n2, a2d);
    k_layer2<<<dim3(NB1), blk, 0, stream>>>(off, deg, ssrc, n2, a2d, b2, out);
}

// Round 21
// 262.909 us; speedup vs baseline: 1.1944x; 1.1944x over previous
//
#include <hip/hip_runtime.h>
#include <math.h>

#define N_NODES 100000
#define IN_DIM  512
#define HID     5
#define HEADS   5
#define C1      25   // HEADS*HID
#define NC      3
#define NEG     0.2f
#define NPB     64   // nodes per block in k_layer1
#define BSH     7    // 128 dsts per bucket
#define NBUCK   ((N_NODES + 127) >> BSH)   // 782
#define NDIG    1024 // padded bucket count (radix digits)
#define NBH2    512  // hist/write blocks (chunking shared by both passes)
#define HTH2    256  // hist/write threads per block
#define BCAP    6144 // bgroup LDS stage capacity (mean 4352, +27 sigma)

typedef float f32x4 __attribute__((ext_vector_type(4)));

// 12-byte per-head chunk of a packed h1p row: [asrc_h | h1[h][0..4]]
struct __attribute__((packed, aligned(4))) H6 { _Float16 a; _Float16 h[5]; };

__device__ __forceinline__ float lrelu(float v) { return v >= 0.f ? v : NEG * v; }

__device__ __forceinline__ void fma4(float acc[C1], f32x4 xv, const float* w) {
#pragma unroll
    for (int j = 0; j < C1; ++j)
        acc[j] = __builtin_fmaf(xv.w, w[3 * C1 + j],
                 __builtin_fmaf(xv.z, w[2 * C1 + j],
                 __builtin_fmaf(xv.y, w[C1 + j],
                 __builtin_fmaf(xv.x, w[j], acc[j]))));
}

// ---- Fused K1 (R19-final): [0..NG) gemm role | [NG..NG+NBH2) hist role.
// Gemm: direct per-lane f32x4 loads (R15-proven; LDS staging tried 3x
// R7/R12/R20, always slower -- kernel is outstanding-miss bound, not
// fetch-bound). Wave w = K-chunk (readfirstlane -> W1 s_load); cross-wave
// LDS reduce; fp16 head-chunk epilogue (12B/head for layer1). ----
__global__ void __launch_bounds__(256)
k_gemm_hist(const float* __restrict__ x, const float* __restrict__ W1,
            const float* __restrict__ as1, const float* __restrict__ ad1,
            const int* __restrict__ ei, int E, int TOT, int NG,
            _Float16* __restrict__ h1p, float* __restrict__ adst,
            int* __restrict__ hist) {
    __shared__ float red[3][64][C1];   // 19.2 KB; aliased as int[] by hist role
    int b = blockIdx.x;
    int tid = threadIdx.x;
    if (b >= NG) {
        // ---- histogram role ----
        int* lh = (int*)red;
        int hb = b - NG;
        for (int i = tid; i < NDIG; i += HTH2) lh[i] = 0;
        __syncthreads();
        int chunk = (TOT + NBH2 - 1) / NBH2;
        int e0 = hb * chunk, e1 = min(e0 + chunk, TOT);
        for (int e = e0 + tid; e < e1; e += HTH2) {
            int d = (e < E) ? ei[E + e] : e - E;
            atomicAdd(&lh[d >> BSH], 1);
        }
        __syncthreads();
        for (int i = tid; i < NDIG; i += HTH2) hist[hb * NDIG + i] = lh[i];
        return;
    }
    // ---- gemm role ----
    int c = __builtin_amdgcn_readfirstlane(tid >> 6);   // wave id = K-chunk
    int l = tid & 63;
    int n = b * 64 + l;
    int nc = n < N_NODES ? n : N_NODES - 1;             // clamp (no early return: sync below)
    const f32x4* xr = (const f32x4*)(x + (size_t)nc * IN_DIM) + c * 32;
    const float* Wb = W1 + (size_t)c * 128 * C1;
    float acc[C1];
#pragma unroll
    for (int j = 0; j < C1; ++j) acc[j] = 0.f;
    for (int L = 0; L < 8; ++L) {         // one 64B line per lane per batch
        f32x4 xv[4];
#pragma unroll
        for (int q = 0; q < 4; ++q) xv[q] = xr[L * 4 + q];
#pragma unroll
        for (int q = 0; q < 4; ++q)
            fma4(acc, xv[q], Wb + (size_t)(L * 4 + q) * 4 * C1);
    }
    if (c > 0) {
#pragma unroll
        for (int j = 0; j < C1; ++j) red[c - 1][l][j] = acc[j];
    }
    __syncthreads();
    if (c == 0 && n < N_NODES) {
#pragma unroll
        for (int j = 0; j < C1; ++j)
            acc[j] += red[0][l][j] + red[1][l][j] + red[2][l][j];
        _Float16 hb16[32];
#pragma unroll
        for (int h = 0; h < HEADS; ++h) {
            float s = 0.f, d = 0.f;
#pragma unroll
            for (int cc = 0; cc < HID; ++cc) {
                s += acc[h * HID + cc] * as1[h * HID + cc];
                d += acc[h * HID + cc] * ad1[h * HID + cc];
                hb16[6 * h + 1 + cc] = (_Float16)acc[h * HID + cc];
            }
            hb16[6 * h] = (_Float16)s;
            adst[n * HEADS + h] = d;
        }
        hb16[30] = (_Float16)0.f; hb16[31] = (_Float16)0.f;
        float4* h4 = (float4*)(h1p + (size_t)n * 32);   // 64B row
        const float4* src = (const float4*)hb16;
#pragma unroll
        for (int q = 0; q < 4; ++q) h4[q] = src[q];
    }
}

// ---- radix: per-digit scan over the 512 hist blocks ----
__global__ void __launch_bounds__(NBH2)
k_colscan(int* __restrict__ hist, int* __restrict__ bcnt) {
    __shared__ int sh[NBH2];
    int d = blockIdx.x, t = threadIdx.x;
    int v = hist[t * NDIG + d];
    sh[t] = v;
    __syncthreads();
    for (int ofs = 1; ofs < NBH2; ofs <<= 1) {
        int u = (t >= ofs) ? sh[t - ofs] : 0;
        __syncthreads();
        sh[t] += u;
        __syncthreads();
    }
    hist[t * NDIG + d] = sh[t] - v;   // exclusive over blocks
    if (t == NBH2 - 1) bcnt[d] = sh[t];
}

// ---- radix: exclusive scan of 1024 bucket counts ----
__global__ void __launch_bounds__(NDIG)
k_boff(const int* __restrict__ bcnt, int* __restrict__ boff) {
    __shared__ int sh[NDIG];
    int t = threadIdx.x;
    int v = bcnt[t];
    sh[t] = v;
    __syncthreads();
    for (int ofs = 1; ofs < NDIG; ofs <<= 1) {
        int u = (t >= ofs) ? sh[t - ofs] : 0;
        __syncthreads();
        sh[t] += u;
        __syncthreads();
    }
    boff[t] = sh[t] - v;
}

// ---- radix pass 2: write packed edges (LDS cursors; chunking == hist role) ----
__global__ void __launch_bounds__(HTH2)
k_write(const int* __restrict__ ei, int E, int TOT, const int* __restrict__ hist,
        const int* __restrict__ boff, int* __restrict__ pk) {
    __shared__ int lbase[NDIG];
    __shared__ int lcur[NDIG];
    int b = blockIdx.x, tid = threadIdx.x;
    for (int i = tid; i < NDIG; i += HTH2) {
        lbase[i] = boff[i] + hist[b * NDIG + i];
        lcur[i] = 0;
    }
    __syncthreads();
    int chunk = (TOT + NBH2 - 1) / NBH2;
    int e0 = b * chunk, e1 = min(e0 + chunk, TOT);
    for (int e = e0 + tid; e < e1; e += HTH2) {
        int s, d;
        if (e < E) { s = ei[e]; d = ei[E + e]; } else { s = d = e - E; }
        int dg = d >> BSH;
        int r = atomicAdd(&lcur[dg], 1);
        pk[lbase[dg] + r] = s | ((d & 127) << 17);
    }
}

// ---- per-bucket regroup by dst; single global read of pk (LDS stage) ----
__global__ void __launch_bounds__(512)
k_bgroup(const int* __restrict__ boff, const int* __restrict__ bcnt,
         const int* __restrict__ pk, int* __restrict__ off, int* __restrict__ deg,
         int* __restrict__ ssrc) {
    __shared__ int stage[BCAP];        // 24 KB
    __shared__ int cnt[128], pref[128], lcur[128];
    int b = blockIdx.x, tid = threadIdx.x;
    int n0 = b << BSH;
    if (tid < 128) cnt[tid] = 0;
    __syncthreads();
    int r0 = boff[b], total = bcnt[b];
    for (int idx = tid; idx < total; idx += 512) {
        int v = pk[r0 + idx];
        if (idx < BCAP) stage[idx] = v;
        atomicAdd(&cnt[(v >> 17) & 127], 1);
    }
    __syncthreads();
    if (tid < 128) pref[tid] = cnt[tid];
    __syncthreads();
    for (int ofs = 1; ofs < 128; ofs <<= 1) {
        int u = 0;
        if (tid < 128 && tid >= ofs) u = pref[tid - ofs];
        __syncthreads();
        if (tid < 128) pref[tid] += u;
        __syncthreads();
    }
    if (tid < 128) {
        int n = n0 + tid;
        if (n < N_NODES) {
            off[n] = r0 + pref[tid] - cnt[tid];
            deg[n] = cnt[tid];
        }
        lcur[tid] = 0;
    }
    __syncthreads();
    for (int idx = tid; idx < total; idx += 512) {
        int v = (idx < BCAP) ? stage[idx] : pk[r0 + idx];
        int dl = (v >> 17) & 127;
        int r = atomicAdd(&lcur[dl], 1);
        ssrc[r0 + pref[dl] - cnt[dl] + r] = v & 0x1FFFF;
    }
}

// ---- Layer 1: per-(dst,head) segment softmax (no max-shift).
// ONE dwordx3 per edge (12B head-chunk); 2-way unrolled edge loop so two
// gathers are in flight per iteration (deeper MLP). ----
__global__ void __launch_bounds__(NPB * HEADS)
k_layer1(const int* __restrict__ off, const int* __restrict__ deg, const int* __restrict__ ssrc,
         const _Float16* __restrict__ h1p, const float* __restrict__ adst,
         const float* __restrict__ b1, const float* __restrict__ W2,
         const float* __restrict__ as2, const float* __restrict__ ad2,
         float4* __restrict__ n2, float* __restrict__ a2d) {
    __shared__ float sh[NPB * C1];
    int tid = threadIdx.x;            // 0..319
    int ln = tid / HEADS, h = tid % HEADS;
    int n = blockIdx.x * NPB + ln;
    if (n < N_NODES) {
        int st = off[n], cnt = deg[n];
        float adn = adst[n * HEADS + h];
        float den = 0.f;
        float num[HID] = {0.f, 0.f, 0.f, 0.f, 0.f};
        const _Float16* hp = (const _Float16*)h1p + 6 * h;   // chunk h of row 0
        int i = 0;
        for (; i + 1 < cnt; i += 2) {
            int s0 = ssrc[st + i];
            int s1 = ssrc[st + i + 1];
            H6 hv0 = *(const H6*)(hp + (size_t)s0 * 32);
            H6 hv1 = *(const H6*)(hp + (size_t)s1 * 32);
            float p0 = __expf(lrelu((float)hv0.a + adn));
            float p1 = __expf(lrelu((float)hv1.a + adn));
            den += p0 + p1;
#pragma unroll
            for (int c = 0; c < HID; ++c) {
                num[c] = __builtin_fmaf(p0, (float)hv0.h[c], num[c]);
                num[c] = __builtin_fmaf(p1, (float)hv1.h[c], num[c]);
            }
        }
        if (i < cnt) {
            int s = ssrc[st + i];
            H6 hv = *(const H6*)(hp + (size_t)s * 32);
            float p = __expf(lrelu((float)hv.a + adn));
            den += p;
#pragma unroll
            for (int c = 0; c < HID; ++c) num[c] = __builtin_fmaf(p, (float)hv.h[c], num[c]);
        }
        float inv = 1.f / den;
#pragma unroll
        for (int c = 0; c < HID; ++c) {
            float v = num[c] * inv + b1[h * HID + c];
            sh[ln * C1 + h * HID + c] = v > 0.f ? v : expm1f(v);
        }
    }
    __syncthreads();
    if (tid < NPB) {
        int nn = blockIdx.x * NPB + tid;
        if (nn < N_NODES) {
            float gg[NC] = {0.f, 0.f, 0.f};
#pragma unroll
            for (int j = 0; j < C1; ++j) {
                float hv = sh[tid * C1 + j];
#pragma unroll
                for (int c = 0; c < NC; ++c) gg[c] += hv * W2[j * NC + c];
            }
            float ssv = 0.f, ddv = 0.f;
#pragma unroll
            for (int c = 0; c < NC; ++c) { ssv += gg[c] * as2[c]; ddv += gg[c] * ad2[c]; }
            n2[nn] = make_float4(ssv, gg[0], gg[1], gg[2]);  // [a2s | g0 g1 g2]
            a2d[nn] = ddv;
        }
    }
}

// ---- Layer 2: per-dst segment softmax (no max-shift), 2-way unrolled ----
__global__ void k_layer2(const int* __restrict__ off, const int* __restrict__ deg,
                         const int* __restrict__ ssrc, const float4* __restrict__ n2,
                         const float* __restrict__ a2d, const float* __restrict__ b2,
                         float* __restrict__ out) {
    int n = blockIdx.x * blockDim.x + threadIdx.x;
    if (n >= N_NODES) return;
    int st = off[n], cnt = deg[n];
    float adn = a2d[n];
    float den = 0.f, num0 = 0.f, num1 = 0.f, num2 = 0.f;
    int i = 0;
    for (; i + 1 < cnt; i += 2) {
        int s0 = ssrc[st + i];
        int s1 = ssrc[st + i + 1];
        float4 g0 = n2[s0];
        float4 g1 = n2[s1];
        float p0 = __expf(lrelu(g0.x + adn));
        float p1 = __expf(lrelu(g1.x + adn));
        den += p0 + p1;
        num0 = __builtin_fmaf(p0, g0.y, __builtin_fmaf(p1, g1.y, num0));
        num1 = __builtin_fmaf(p0, g0.z, __builtin_fmaf(p1, g1.z, num1));
        num2 = __builtin_fmaf(p0, g0.w, __builtin_fmaf(p1, g1.w, num2));
    }
    if (i < cnt) {
        int s = ssrc[st + i];
        float4 gv = n2[s];
        float p = __expf(lrelu(gv.x + adn));
        den += p;
        num0 = __builtin_fmaf(p, gv.y, num0);
        num1 = __builtin_fmaf(p, gv.z, num1);
        num2 = __builtin_fmaf(p, gv.w, num2);
    }
    float inv = 1.f / den;
    float vv[NC] = {num0 * inv + b2[0], num1 * inv + b2[1], num2 * inv + b2[2]};
#pragma unroll
    for (int c = 0; c < NC; ++c) {
        float v = vv[c];
        out[n * NC + c] = (v >= 0.f) ? -log1pf(__expf(-v)) : v - log1pf(__expf(v));
    }
}

extern "C" void kernel_launch(void* const* d_in, const int* in_sizes, int n_in,
                              void* d_out, int out_size, void* d_ws, size_t ws_size,
                              hipStream_t stream) {
    const float* x   = (const float*)d_in[0];
    const int*   ei  = (const int*)d_in[1];
    const float* W1  = (const float*)d_in[2];
    const float* as1 = (const float*)d_in[3];
    const float* ad1 = (const float*)d_in[4];
    const float* b1  = (const float*)d_in[5];
    const float* W2  = (const float*)d_in[6];
    const float* as2 = (const float*)d_in[7];
    const float* ad2 = (const float*)d_in[8];
    const float* b2  = (const float*)d_in[9];
    float* out = (float*)d_out;
    int E = in_sizes[1] / 2;
    int TOT = E + N_NODES;

    int*   iws = (int*)d_ws;
    float* fws = (float*)d_ws;
    // ints (no memset needed: every word written before read; no overlays)
    int* hist = iws;                       // NBH2*NDIG = 524,288
    int* bcnt = iws + 524288;              // 1024
    int* boff = iws + 525312;              // 1024
    int* off  = iws + 526336;              // N
    int* deg  = iws + 626336;              // N
    int* pk   = iws + 726336;              // TOT
    int* ssrc = pk + TOT;                  // TOT
    size_t fbase = 726336 + 2 * (size_t)TOT;   // ~7.33M floats
    _Float16* h1p = (_Float16*)(fws + fbase);  // N*32 halfs = N*16 floats
    float*  adst = fws + fbase + 1600000;  // N*5
    float4* n2   = (float4*)(fws + fbase + 2100000); // N float4
    float*  a2d  = fws + fbase + 2500000;  // N  (end fbase+2.6M ~ 39.7 MB)

    dim3 blk(256);
    int NB1 = (N_NODES + 255) / 256;  // 391
    int NG  = (N_NODES + 63) / 64;    // 1563 gemm blocks
    k_gemm_hist<<<dim3(NG + NBH2), dim3(256), 0, stream>>>(
        x, W1, as1, ad1, ei, E, TOT, NG, h1p, adst, hist);
    k_colscan<<<dim3(NDIG), dim3(NBH2), 0, stream>>>(hist, bcnt);
    k_boff<<<dim3(1), dim3(NDIG), 0, stream>>>(bcnt, boff);
    k_write<<<dim3(NBH2), dim3(HTH2), 0, stream>>>(ei, E, TOT, hist, boff, pk);
    k_bgroup<<<dim3(NBUCK), dim3(512), 0, stream>>>(boff, bcnt, pk, off, deg, ssrc);
    k_layer1<<<dim3((N_NODES + NPB - 1) / NPB), dim3(NPB * HEADS), 0, stream>>>(
        off, deg, ssrc, h1p, adst, b1, W2, as2, ad2, n2, a2d);
    k_layer2<<<dim3(NB1), blk, 0, stream>>>(off, deg, ssrc, n2, a2d, b2, out);
}

// Round 22
// 242.208 us; speedup vs baseline: 1.2964x; 1.0855x over previous
//
#include <hip/hip_runtime.h>
#include <math.h>

#define N_NODES 100000
#define IN_DIM  512
#define HID     5
#define HEADS   5
#define C1      25   // HEADS*HID
#define NC      3
#define NEG     0.2f
#define NPB     64   // nodes per block in k_layer1
#define BSH     7    // 128 dsts per bucket
#define NBUCK   ((N_NODES + 127) >> BSH)   // 782
#define NDIG    1024 // padded bucket count (radix digits)
#define NBH2    512  // hist/write blocks (chunking shared by both passes)
#define HTH2    256  // hist/write threads per block
#define BCAP    6144 // bgroup LDS stage capacity (mean 4352, +27 sigma)

typedef float f32x4 __attribute__((ext_vector_type(4)));

// 12-byte per-head chunk of a packed h1p row: [asrc_h | h1[h][0..4]]
struct __attribute__((packed, aligned(4))) H6 { _Float16 a; _Float16 h[5]; };

__device__ __forceinline__ float lrelu(float v) { return v >= 0.f ? v : NEG * v; }

__device__ __forceinline__ void fma4(float acc[C1], f32x4 xv, const float* w) {
#pragma unroll
    for (int j = 0; j < C1; ++j)
        acc[j] = __builtin_fmaf(xv.w, w[3 * C1 + j],
                 __builtin_fmaf(xv.z, w[2 * C1 + j],
                 __builtin_fmaf(xv.y, w[C1 + j],
                 __builtin_fmaf(xv.x, w[j], acc[j]))));
}

// ---- Fused K1 (final): [0..NG) gemm role | [NG..NG+NBH2) hist role. ----
__global__ void __launch_bounds__(256)
k_gemm_hist(const float* __restrict__ x, const float* __restrict__ W1,
            const float* __restrict__ as1, const float* __restrict__ ad1,
            const int* __restrict__ ei, int E, int TOT, int NG,
            _Float16* __restrict__ h1p, float* __restrict__ adst,
            int* __restrict__ hist) {
    __shared__ float red[3][64][C1];   // 19.2 KB; aliased as int[] by hist role
    int b = blockIdx.x;
    int tid = threadIdx.x;
    if (b >= NG) {
        // ---- histogram role ----
        int* lh = (int*)red;
        int hb = b - NG;
        for (int i = tid; i < NDIG; i += HTH2) lh[i] = 0;
        __syncthreads();
        int chunk = (TOT + NBH2 - 1) / NBH2;
        int e0 = hb * chunk, e1 = min(e0 + chunk, TOT);
        for (int e = e0 + tid; e < e1; e += HTH2) {
            int d = (e < E) ? ei[E + e] : e - E;
            atomicAdd(&lh[d >> BSH], 1);
        }
        __syncthreads();
        for (int i = tid; i < NDIG; i += HTH2) hist[hb * NDIG + i] = lh[i];
        return;
    }
    // ---- gemm role ----
    int c = __builtin_amdgcn_readfirstlane(tid >> 6);   // wave id = K-chunk
    int l = tid & 63;
    int n = b * 64 + l;
    int nc = n < N_NODES ? n : N_NODES - 1;             // clamp (no early return: sync below)
    const f32x4* xr = (const f32x4*)(x + (size_t)nc * IN_DIM) + c * 32;
    const float* Wb = W1 + (size_t)c * 128 * C1;
    float acc[C1];
#pragma unroll
    for (int j = 0; j < C1; ++j) acc[j] = 0.f;
    for (int L = 0; L < 8; ++L) {         // one 64B line per lane per batch
        f32x4 xv[4];
#pragma unroll
        for (int q = 0; q < 4; ++q) xv[q] = xr[L * 4 + q];
#pragma unroll
        for (int q = 0; q < 4; ++q)
            fma4(acc, xv[q], Wb + (size_t)(L * 4 + q) * 4 * C1);
    }
    if (c > 0) {
#pragma unroll
        for (int j = 0; j < C1; ++j) red[c - 1][l][j] = acc[j];
    }
    __syncthreads();
    if (c == 0 && n < N_NODES) {
#pragma unroll
        for (int j = 0; j < C1; ++j)
            acc[j] += red[0][l][j] + red[1][l][j] + red[2][l][j];
        _Float16 hb16[32];
#pragma unroll
        for (int h = 0; h < HEADS; ++h) {
            float s = 0.f, d = 0.f;
#pragma unroll
            for (int cc = 0; cc < HID; ++cc) {
                s += acc[h * HID + cc] * as1[h * HID + cc];
                d += acc[h * HID + cc] * ad1[h * HID + cc];
                hb16[6 * h + 1 + cc] = (_Float16)acc[h * HID + cc];
            }
            hb16[6 * h] = (_Float16)s;
            adst[n * HEADS + h] = d;
        }
        hb16[30] = (_Float16)0.f; hb16[31] = (_Float16)0.f;
        float4* h4 = (float4*)(h1p + (size_t)n * 32);   // 64B row
        const float4* src = (const float4*)hb16;
#pragma unroll
        for (int q = 0; q < 4; ++q) h4[q] = src[q];
    }
}

// ---- radix: per-digit scan over the 512 hist blocks ----
__global__ void __launch_bounds__(NBH2)
k_colscan(int* __restrict__ hist, int* __restrict__ bcnt) {
    __shared__ int sh[NBH2];
    int d = blockIdx.x, t = threadIdx.x;
    int v = hist[t * NDIG + d];
    sh[t] = v;
    __syncthreads();
    for (int ofs = 1; ofs < NBH2; ofs <<= 1) {
        int u = (t >= ofs) ? sh[t - ofs] : 0;
        __syncthreads();
        sh[t] += u;
        __syncthreads();
    }
    hist[t * NDIG + d] = sh[t] - v;   // exclusive over blocks
    if (t == NBH2 - 1) bcnt[d] = sh[t];
}

// ---- radix pass 2: write packed edges. Per-block LDS scan of bcnt ->
// global digit offsets (k_boff folded in; redundant per block but ~free). ----
__global__ void __launch_bounds__(HTH2)
k_write(const int* __restrict__ ei, int E, int TOT, const int* __restrict__ hist,
        const int* __restrict__ bcnt, int* __restrict__ pk) {
    __shared__ int lbase[NDIG];
    __shared__ int lcur[NDIG];
    __shared__ int ssum[HTH2];
    int b = blockIdx.x, t = threadIdx.x;
    // two-level exclusive scan of bcnt[1024]: thread t owns digits 4t..4t+3
    int q0 = bcnt[4 * t], q1 = bcnt[4 * t + 1], q2 = bcnt[4 * t + 2], q3 = bcnt[4 * t + 3];
    int s = q0 + q1 + q2 + q3;
    ssum[t] = s;
    __syncthreads();
    for (int ofs = 1; ofs < HTH2; ofs <<= 1) {
        int u = (t >= ofs) ? ssum[t - ofs] : 0;
        __syncthreads();
        ssum[t] += u;
        __syncthreads();
    }
    int base = ssum[t] - s;            // exclusive over quads
    const int* hb = hist + (size_t)b * NDIG;
    lbase[4 * t]     = base + hb[4 * t];
    lbase[4 * t + 1] = base + q0 + hb[4 * t + 1];
    lbase[4 * t + 2] = base + q0 + q1 + hb[4 * t + 2];
    lbase[4 * t + 3] = base + q0 + q1 + q2 + hb[4 * t + 3];
    lcur[4 * t] = 0; lcur[4 * t + 1] = 0; lcur[4 * t + 2] = 0; lcur[4 * t + 3] = 0;
    __syncthreads();
    int chunk = (TOT + NBH2 - 1) / NBH2;
    int e0 = b * chunk, e1 = min(e0 + chunk, TOT);
    for (int e = e0 + t; e < e1; e += HTH2) {
        int src, d;
        if (e < E) { src = ei[e]; d = ei[E + e]; } else { src = d = e - E; }
        int dg = d >> BSH;
        int r = atomicAdd(&lcur[dg], 1);
        pk[lbase[dg] + r] = src | ((d & 127) << 17);
    }
}

// ---- per-bucket regroup by dst; r0 computed from bcnt (boff folded in) ----
__global__ void __launch_bounds__(512)
k_bgroup(const int* __restrict__ bcnt, const int* __restrict__ pk,
         int* __restrict__ off, int* __restrict__ deg, int* __restrict__ ssrc) {
    __shared__ int stage[BCAP];        // 24 KB
    __shared__ int rsum[512];
    __shared__ int cnt[128], pref[128], lcur[128];
    int b = blockIdx.x, tid = threadIdx.x;
    int n0 = b << BSH;
    // r0 = sum(bcnt[0..b)) via strided partials + tree reduce
    int part = 0;
    for (int i = tid; i < b; i += 512) part += bcnt[i];
    rsum[tid] = part;
    if (tid < 128) cnt[tid] = 0;
    __syncthreads();
    for (int ofs = 256; ofs > 0; ofs >>= 1) {
        if (tid < ofs) rsum[tid] += rsum[tid + ofs];
        __syncthreads();
    }
    int r0 = rsum[0];
    int total = bcnt[b];
    for (int idx = tid; idx < total; idx += 512) {
        int v = pk[r0 + idx];
        if (idx < BCAP) stage[idx] = v;
        atomicAdd(&cnt[(v >> 17) & 127], 1);
    }
    __syncthreads();
    if (tid < 128) pref[tid] = cnt[tid];
    __syncthreads();
    for (int ofs = 1; ofs < 128; ofs <<= 1) {
        int u = 0;
        if (tid < 128 && tid >= ofs) u = pref[tid - ofs];
        __syncthreads();
        if (tid < 128) pref[tid] += u;
        __syncthreads();
    }
    if (tid < 128) {
        int n = n0 + tid;
        if (n < N_NODES) {
            off[n] = r0 + pref[tid] - cnt[tid];
            deg[n] = cnt[tid];
        }
        lcur[tid] = 0;
    }
    __syncthreads();
    for (int idx = tid; idx < total; idx += 512) {
        int v = (idx < BCAP) ? stage[idx] : pk[r0 + idx];
        int dl = (v >> 17) & 127;
        int r = atomicAdd(&lcur[dl], 1);
        ssrc[r0 + pref[dl] - cnt[dl] + r] = v & 0x1FFFF;
    }
}

// ---- Layer 1: per-(dst,head) segment softmax (no max-shift).
// ONE dwordx3 per edge (12B head-chunk); 4-way unrolled (4 gathers in
// flight), 2/1-way tails. ----
__global__ void __launch_bounds__(NPB * HEADS)
k_layer1(const int* __restrict__ off, const int* __restrict__ deg, const int* __restrict__ ssrc,
         const _Float16* __restrict__ h1p, const float* __restrict__ adst,
         const float* __restrict__ b1, const float* __restrict__ W2,
         const float* __restrict__ as2, const float* __restrict__ ad2,
         float4* __restrict__ n2, float* __restrict__ a2d) {
    __shared__ float sh[NPB * C1];
    int tid = threadIdx.x;            // 0..319
    int ln = tid / HEADS, h = tid % HEADS;
    int n = blockIdx.x * NPB + ln;
    if (n < N_NODES) {
        int st = off[n], cnt = deg[n];
        float adn = adst[n * HEADS + h];
        float den = 0.f;
        float num[HID] = {0.f, 0.f, 0.f, 0.f, 0.f};
        const _Float16* hp = (const _Float16*)h1p + 6 * h;   // chunk h of row 0
        int i = 0;
        for (; i + 3 < cnt; i += 4) {
            int s0 = ssrc[st + i];
            int s1 = ssrc[st + i + 1];
            int s2 = ssrc[st + i + 2];
            int s3 = ssrc[st + i + 3];
            H6 v0 = *(const H6*)(hp + (size_t)s0 * 32);
            H6 v1 = *(const H6*)(hp + (size_t)s1 * 32);
            H6 v2 = *(const H6*)(hp + (size_t)s2 * 32);
            H6 v3 = *(const H6*)(hp + (size_t)s3 * 32);
            float p0 = __expf(lrelu((float)v0.a + adn));
            float p1 = __expf(lrelu((float)v1.a + adn));
            float p2 = __expf(lrelu((float)v2.a + adn));
            float p3 = __expf(lrelu((float)v3.a + adn));
            den += (p0 + p1) + (p2 + p3);
#pragma unroll
            for (int c = 0; c < HID; ++c) {
                num[c] = __builtin_fmaf(p0, (float)v0.h[c], num[c]);
                num[c] = __builtin_fmaf(p1, (float)v1.h[c], num[c]);
                num[c] = __builtin_fmaf(p2, (float)v2.h[c], num[c]);
                num[c] = __builtin_fmaf(p3, (float)v3.h[c], num[c]);
            }
        }
        for (; i + 1 < cnt; i += 2) {
            int s0 = ssrc[st + i];
            int s1 = ssrc[st + i + 1];
            H6 v0 = *(const H6*)(hp + (size_t)s0 * 32);
            H6 v1 = *(const H6*)(hp + (size_t)s1 * 32);
            float p0 = __expf(lrelu((float)v0.a + adn));
            float p1 = __expf(lrelu((float)v1.a + adn));
            den += p0 + p1;
#pragma unroll
            for (int c = 0; c < HID; ++c) {
                num[c] = __builtin_fmaf(p0, (float)v0.h[c], num[c]);
                num[c] = __builtin_fmaf(p1, (float)v1.h[c], num[c]);
            }
        }
        if (i < cnt) {
            int s = ssrc[st + i];
            H6 hv = *(const H6*)(hp + (size_t)s * 32);
            float p = __expf(lrelu((float)hv.a + adn));
            den += p;
#pragma unroll
            for (int c = 0; c < HID; ++c) num[c] = __builtin_fmaf(p, (float)hv.h[c], num[c]);
        }
        float inv = 1.f / den;
#pragma unroll
        for (int c = 0; c < HID; ++c) {
            float v = num[c] * inv + b1[h * HID + c];
            sh[ln * C1 + h * HID + c] = v > 0.f ? v : expm1f(v);
        }
    }
    __syncthreads();
    if (tid < NPB) {
        int nn = blockIdx.x * NPB + tid;
        if (nn < N_NODES) {
            float gg[NC] = {0.f, 0.f, 0.f};
#pragma unroll
            for (int j = 0; j < C1; ++j) {
                float hv = sh[tid * C1 + j];
#pragma unroll
                for (int c = 0; c < NC; ++c) gg[c] += hv * W2[j * NC + c];
            }
            float ssv = 0.f, ddv = 0.f;
#pragma unroll
            for (int c = 0; c < NC; ++c) { ssv += gg[c] * as2[c]; ddv += gg[c] * ad2[c]; }
            n2[nn] = make_float4(ssv, gg[0], gg[1], gg[2]);  // [a2s | g0 g1 g2]
            a2d[nn] = ddv;
        }
    }
}

// ---- Layer 2: per-dst segment softmax (no max-shift), 4-way unrolled ----
__global__ void k_layer2(const int* __restrict__ off, const int* __restrict__ deg,
                         const int* __restrict__ ssrc, const float4* __restrict__ n2,
                         const float* __restrict__ a2d, const float* __restrict__ b2,
                         float* __restrict__ out) {
    int n = blockIdx.x * blockDim.x + threadIdx.x;
    if (n >= N_NODES) return;
    int st = off[n], cnt = deg[n];
    float adn = a2d[n];
    float den = 0.f, num0 = 0.f, num1 = 0.f, num2 = 0.f;
    int i = 0;
    for (; i + 3 < cnt; i += 4) {
        int s0 = ssrc[st + i];
        int s1 = ssrc[st + i + 1];
        int s2 = ssrc[st + i + 2];
        int s3 = ssrc[st + i + 3];
        float4 g0 = n2[s0];
        float4 g1 = n2[s1];
        float4 g2 = n2[s2];
        float4 g3 = n2[s3];
        float p0 = __expf(lrelu(g0.x + adn));
        float p1 = __expf(lrelu(g1.x + adn));
        float p2 = __expf(lrelu(g2.x + adn));
        float p3 = __expf(lrelu(g3.x + adn));
        den += (p0 + p1) + (p2 + p3);
        num0 = __builtin_fmaf(p0, g0.y, __builtin_fmaf(p1, g1.y,
               __builtin_fmaf(p2, g2.y, __builtin_fmaf(p3, g3.y, num0))));
        num1 = __builtin_fmaf(p0, g0.z, __builtin_fmaf(p1, g1.z,
               __builtin_fmaf(p2, g2.z, __builtin_fmaf(p3, g3.z, num1))));
        num2 = __builtin_fmaf(p0, g0.w, __builtin_fmaf(p1, g1.w,
               __builtin_fmaf(p2, g2.w, __builtin_fmaf(p3, g3.w, num2))));
    }
    for (; i < cnt; ++i) {
        int s = ssrc[st + i];
        float4 gv = n2[s];
        float p = __expf(lrelu(gv.x + adn));
        den += p;
        num0 = __builtin_fmaf(p, gv.y, num0);
        num1 = __builtin_fmaf(p, gv.z, num1);
        num2 = __builtin_fmaf(p, gv.w, num2);
    }
    float inv = 1.f / den;
    float vv[NC] = {num0 * inv + b2[0], num1 * inv + b2[1], num2 * inv + b2[2]};
#pragma unroll
    for (int c = 0; c < NC; ++c) {
        float v = vv[c];
        out[n * NC + c] = (v >= 0.f) ? -log1pf(__expf(-v)) : v - log1pf(__expf(v));
    }
}

extern "C" void kernel_launch(void* const* d_in, const int* in_sizes, int n_in,
                              void* d_out, int out_size, void* d_ws, size_t ws_size,
                              hipStream_t stream) {
    const float* x   = (const float*)d_in[0];
    const int*   ei  = (const int*)d_in[1];
    const float* W1  = (const float*)d_in[2];
    const float* as1 = (const float*)d_in[3];
    const float* ad1 = (const float*)d_in[4];
    const float* b1  = (const float*)d_in[5];
    const float* W2  = (const float*)d_in[6];
    const float* as2 = (const float*)d_in[7];
    const float* ad2 = (const float*)d_in[8];
    const float* b2  = (const float*)d_in[9];
    float* out = (float*)d_out;
    int E = in_sizes[1] / 2;
    int TOT = E + N_NODES;

    int*   iws = (int*)d_ws;
    float* fws = (float*)d_ws;
    // ints (no memset needed: every word written before read; no overlays)
    int* hist = iws;                       // NBH2*NDIG = 524,288
    int* bcnt = iws + 524288;              // 1024
    int* off  = iws + 526336;              // N
    int* deg  = iws + 626336;              // N
    int* pk   = iws + 726336;              // TOT
    int* ssrc = pk + TOT;                  // TOT
    size_t fbase = 726336 + 2 * (size_t)TOT;   // ~7.33M floats
    _Float16* h1p = (_Float16*)(fws + fbase);  // N*32 halfs = N*16 floats
    float*  adst = fws + fbase + 1600000;  // N*5
    float4* n2   = (float4*)(fws + fbase + 2100000); // N float4
    float*  a2d  = fws + fbase + 2500000;  // N  (end fbase+2.6M ~ 39.7 MB)

    dim3 blk(256);
    int NB1 = (N_NODES + 255) / 256;  // 391
    int NG  = (N_NODES + 63) / 64;    // 1563 gemm blocks
    k_gemm_hist<<<dim3(NG + NBH2), dim3(256), 0, stream>>>(
        x, W1, as1, ad1, ei, E, TOT, NG, h1p, adst, hist);
    k_colscan<<<dim3(NDIG), dim3(NBH2), 0, stream>>>(hist, bcnt);
    k_write<<<dim3(NBH2), dim3(HTH2), 0, stream>>>(ei, E, TOT, hist, bcnt, pk);
    k_bgroup<<<dim3(NBUCK), dim3(512), 0, stream>>>(bcnt, pk, off, deg, ssrc);
    k_layer1<<<dim3((N_NODES + NPB - 1) / NPB), dim3(NPB * HEADS), 0, stream>>>(
        off, deg, ssrc, h1p, adst, b1, W2, as2, ad2, n2, a2d);
    k_layer2<<<dim3(NB1), blk, 0, stream>>>(off, deg, ssrc, n2, a2d, b2, out);
}

// Round 23
// 232.064 us; speedup vs baseline: 1.3531x; 1.0437x over previous
//
#include <hip/hip_runtime.h>
#include <math.h>

#define N_NODES 100000
#define IN_DIM  512
#define HID     5
#define HEADS   5
#define C1      25   // HEADS*HID
#define NC      3
#define NEG     0.2f
#define NPB     64   // nodes per block in k_layer1
#define BSH     7    // 128 dsts per bucket
#define NBUCK   ((N_NODES + 127) >> BSH)   // 782
#define NDIG    1024 // padded bucket count (radix digits)
#define NBH2    512  // hist/write blocks (chunking shared by both passes)
#define HTH2    256  // hist/write threads per block
#define BCAP    6144 // bgroup LDS stage capacity (mean 4352, +27 sigma)

typedef float f32x4 __attribute__((ext_vector_type(4)));

// 12-byte per-head chunk of a packed h1p row: [asrc_h | h1[h][0..4]]
struct __attribute__((packed, aligned(4))) H6 { _Float16 a; _Float16 h[5]; };

__device__ __forceinline__ float lrelu(float v) { return v >= 0.f ? v : NEG * v; }

__device__ __forceinline__ void fma4(float acc[C1], f32x4 xv, const float* w) {
#pragma unroll
    for (int j = 0; j < C1; ++j)
        acc[j] = __builtin_fmaf(xv.w, w[3 * C1 + j],
                 __builtin_fmaf(xv.z, w[2 * C1 + j],
                 __builtin_fmaf(xv.y, w[C1 + j],
                 __builtin_fmaf(xv.x, w[j], acc[j]))));
}

// ---- Fused K1 (final): [0..NG) gemm role | [NG..NG+NBH2) hist role. ----
__global__ void __launch_bounds__(256)
k_gemm_hist(const float* __restrict__ x, const float* __restrict__ W1,
            const float* __restrict__ as1, const float* __restrict__ ad1,
            const int* __restrict__ ei, int E, int TOT, int NG,
            _Float16* __restrict__ h1p, float* __restrict__ adst,
            int* __restrict__ hist) {
    __shared__ float red[3][64][C1];   // 19.2 KB; aliased as int[] by hist role
    int b = blockIdx.x;
    int tid = threadIdx.x;
    if (b >= NG) {
        // ---- histogram role ----
        int* lh = (int*)red;
        int hb = b - NG;
        for (int i = tid; i < NDIG; i += HTH2) lh[i] = 0;
        __syncthreads();
        int chunk = (TOT + NBH2 - 1) / NBH2;
        int e0 = hb * chunk, e1 = min(e0 + chunk, TOT);
        for (int e = e0 + tid; e < e1; e += HTH2) {
            int d = (e < E) ? ei[E + e] : e - E;
            atomicAdd(&lh[d >> BSH], 1);
        }
        __syncthreads();
        for (int i = tid; i < NDIG; i += HTH2) hist[hb * NDIG + i] = lh[i];
        return;
    }
    // ---- gemm role ----
    int c = __builtin_amdgcn_readfirstlane(tid >> 6);   // wave id = K-chunk
    int l = tid & 63;
    int n = b * 64 + l;
    int nc = n < N_NODES ? n : N_NODES - 1;             // clamp (no early return: sync below)
    const f32x4* xr = (const f32x4*)(x + (size_t)nc * IN_DIM) + c * 32;
    const float* Wb = W1 + (size_t)c * 128 * C1;
    float acc[C1];
#pragma unroll
    for (int j = 0; j < C1; ++j) acc[j] = 0.f;
    for (int L = 0; L < 8; ++L) {         // one 64B line per lane per batch
        f32x4 xv[4];
#pragma unroll
        for (int q = 0; q < 4; ++q) xv[q] = xr[L * 4 + q];
#pragma unroll
        for (int q = 0; q < 4; ++q)
            fma4(acc, xv[q], Wb + (size_t)(L * 4 + q) * 4 * C1);
    }
    if (c > 0) {
#pragma unroll
        for (int j = 0; j < C1; ++j) red[c - 1][l][j] = acc[j];
    }
    __syncthreads();
    if (c == 0 && n < N_NODES) {
#pragma unroll
        for (int j = 0; j < C1; ++j)
            acc[j] += red[0][l][j] + red[1][l][j] + red[2][l][j];
        _Float16 hb16[32];
#pragma unroll
        for (int h = 0; h < HEADS; ++h) {
            float s = 0.f, d = 0.f;
#pragma unroll
            for (int cc = 0; cc < HID; ++cc) {
                s += acc[h * HID + cc] * as1[h * HID + cc];
                d += acc[h * HID + cc] * ad1[h * HID + cc];
                hb16[6 * h + 1 + cc] = (_Float16)acc[h * HID + cc];
            }
            hb16[6 * h] = (_Float16)s;
            adst[n * HEADS + h] = d;
        }
        hb16[30] = (_Float16)0.f; hb16[31] = (_Float16)0.f;
        float4* h4 = (float4*)(h1p + (size_t)n * 32);   // 64B row
        const float4* src = (const float4*)hb16;
#pragma unroll
        for (int q = 0; q < 4; ++q) h4[q] = src[q];
    }
}

// ---- radix: per-digit scan over the 512 hist blocks ----
__global__ void __launch_bounds__(NBH2)
k_colscan(int* __restrict__ hist, int* __restrict__ bcnt) {
    __shared__ int sh[NBH2];
    int d = blockIdx.x, t = threadIdx.x;
    int v = hist[t * NDIG + d];
    sh[t] = v;
    __syncthreads();
    for (int ofs = 1; ofs < NBH2; ofs <<= 1) {
        int u = (t >= ofs) ? sh[t - ofs] : 0;
        __syncthreads();
        sh[t] += u;
        __syncthreads();
    }
    hist[t * NDIG + d] = sh[t] - v;   // exclusive over blocks
    if (t == NBH2 - 1) bcnt[d] = sh[t];
}

// ---- radix pass 2: write packed edges. Per-block LDS scan of bcnt ->
// global digit offsets (k_boff folded in; redundant per block but ~free). ----
__global__ void __launch_bounds__(HTH2)
k_write(const int* __restrict__ ei, int E, int TOT, const int* __restrict__ hist,
        const int* __restrict__ bcnt, int* __restrict__ pk) {
    __shared__ int lbase[NDIG];
    __shared__ int lcur[NDIG];
    __shared__ int ssum[HTH2];
    int b = blockIdx.x, t = threadIdx.x;
    // two-level exclusive scan of bcnt[1024]: thread t owns digits 4t..4t+3
    int q0 = bcnt[4 * t], q1 = bcnt[4 * t + 1], q2 = bcnt[4 * t + 2], q3 = bcnt[4 * t + 3];
    int s = q0 + q1 + q2 + q3;
    ssum[t] = s;
    __syncthreads();
    for (int ofs = 1; ofs < HTH2; ofs <<= 1) {
        int u = (t >= ofs) ? ssum[t - ofs] : 0;
        __syncthreads();
        ssum[t] += u;
        __syncthreads();
    }
    int base = ssum[t] - s;            // exclusive over quads
    const int* hb = hist + (size_t)b * NDIG;
    lbase[4 * t]     = base + hb[4 * t];
    lbase[4 * t + 1] = base + q0 + hb[4 * t + 1];
    lbase[4 * t + 2] = base + q0 + q1 + hb[4 * t + 2];
    lbase[4 * t + 3] = base + q0 + q1 + q2 + hb[4 * t + 3];
    lcur[4 * t] = 0; lcur[4 * t + 1] = 0; lcur[4 * t + 2] = 0; lcur[4 * t + 3] = 0;
    __syncthreads();
    int chunk = (TOT + NBH2 - 1) / NBH2;
    int e0 = b * chunk, e1 = min(e0 + chunk, TOT);
    for (int e = e0 + t; e < e1; e += HTH2) {
        int src, d;
        if (e < E) { src = ei[e]; d = ei[E + e]; } else { src = d = e - E; }
        int dg = d >> BSH;
        int r = atomicAdd(&lcur[dg], 1);
        pk[lbase[dg] + r] = src | ((d & 127) << 17);
    }
}

// ---- per-bucket regroup by dst; r0 computed from bcnt (boff folded in) ----
__global__ void __launch_bounds__(512)
k_bgroup(const int* __restrict__ bcnt, const int* __restrict__ pk,
         int* __restrict__ off, int* __restrict__ deg, int* __restrict__ ssrc) {
    __shared__ int stage[BCAP];        // 24 KB
    __shared__ int rsum[512];
    __shared__ int cnt[128], pref[128], lcur[128];
    int b = blockIdx.x, tid = threadIdx.x;
    int n0 = b << BSH;
    // r0 = sum(bcnt[0..b)) via strided partials + tree reduce
    int part = 0;
    for (int i = tid; i < b; i += 512) part += bcnt[i];
    rsum[tid] = part;
    if (tid < 128) cnt[tid] = 0;
    __syncthreads();
    for (int ofs = 256; ofs > 0; ofs >>= 1) {
        if (tid < ofs) rsum[tid] += rsum[tid + ofs];
        __syncthreads();
    }
    int r0 = rsum[0];
    int total = bcnt[b];
    for (int idx = tid; idx < total; idx += 512) {
        int v = pk[r0 + idx];
        if (idx < BCAP) stage[idx] = v;
        atomicAdd(&cnt[(v >> 17) & 127], 1);
    }
    __syncthreads();
    if (tid < 128) pref[tid] = cnt[tid];
    __syncthreads();
    for (int ofs = 1; ofs < 128; ofs <<= 1) {
        int u = 0;
        if (tid < 128 && tid >= ofs) u = pref[tid - ofs];
        __syncthreads();
        if (tid < 128) pref[tid] += u;
        __syncthreads();
    }
    if (tid < 128) {
        int n = n0 + tid;
        if (n < N_NODES) {
            off[n] = r0 + pref[tid] - cnt[tid];
            deg[n] = cnt[tid];
        }
        lcur[tid] = 0;
    }
    __syncthreads();
    int idx = tid;
    for (; idx + 512 < total; idx += 1024) {
        int v0 = (idx < BCAP) ? stage[idx] : pk[r0 + idx];
        int i1 = idx + 512;
        int v1 = (i1 < BCAP) ? stage[i1] : pk[r0 + i1];
        int dl0 = (v0 >> 17) & 127;
        int dl1 = (v1 >> 17) & 127;
        int rr0 = atomicAdd(&lcur[dl0], 1);
        int rr1 = atomicAdd(&lcur[dl1], 1);
        ssrc[r0 + pref[dl0] - cnt[dl0] + rr0] = v0 & 0x1FFFF;
        ssrc[r0 + pref[dl1] - cnt[dl1] + rr1] = v1 & 0x1FFFF;
    }
    if (idx < total) {
        int v = (idx < BCAP) ? stage[idx] : pk[r0 + idx];
        int dl = (v >> 17) & 127;
        int r = atomicAdd(&lcur[dl], 1);
        ssrc[r0 + pref[dl] - cnt[dl] + r] = v & 0x1FFFF;
    }
}

// ---- Layer 1: per-(dst,head) segment softmax (no max-shift).
// ONE dwordx3 per edge (12B head-chunk); 8-way unrolled (8 gathers in
// flight), 4/2/1-way tails. ----
__global__ void __launch_bounds__(NPB * HEADS)
k_layer1(const int* __restrict__ off, const int* __restrict__ deg, const int* __restrict__ ssrc,
         const _Float16* __restrict__ h1p, const float* __restrict__ adst,
         const float* __restrict__ b1, const float* __restrict__ W2,
         const float* __restrict__ as2, const float* __restrict__ ad2,
         float4* __restrict__ n2, float* __restrict__ a2d) {
    __shared__ float sh[NPB * C1];
    int tid = threadIdx.x;            // 0..319
    int ln = tid / HEADS, h = tid % HEADS;
    int n = blockIdx.x * NPB + ln;
    if (n < N_NODES) {
        int st = off[n], cnt = deg[n];
        float adn = adst[n * HEADS + h];
        float den = 0.f;
        float num[HID] = {0.f, 0.f, 0.f, 0.f, 0.f};
        const _Float16* hp = (const _Float16*)h1p + 6 * h;   // chunk h of row 0
        int i = 0;
        for (; i + 7 < cnt; i += 8) {
            H6 v[8];
#pragma unroll
            for (int u = 0; u < 8; ++u) {
                int s = ssrc[st + i + u];
                v[u] = *(const H6*)(hp + (size_t)s * 32);
            }
            float ps = 0.f;
#pragma unroll
            for (int u = 0; u < 8; ++u) {
                float p = __expf(lrelu((float)v[u].a + adn));
                ps += p;
#pragma unroll
                for (int c = 0; c < HID; ++c)
                    num[c] = __builtin_fmaf(p, (float)v[u].h[c], num[c]);
            }
            den += ps;
        }
        for (; i + 3 < cnt; i += 4) {
            H6 v[4];
#pragma unroll
            for (int u = 0; u < 4; ++u) {
                int s = ssrc[st + i + u];
                v[u] = *(const H6*)(hp + (size_t)s * 32);
            }
#pragma unroll
            for (int u = 0; u < 4; ++u) {
                float p = __expf(lrelu((float)v[u].a + adn));
                den += p;
#pragma unroll
                for (int c = 0; c < HID; ++c)
                    num[c] = __builtin_fmaf(p, (float)v[u].h[c], num[c]);
            }
        }
        for (; i < cnt; ++i) {
            int s = ssrc[st + i];
            H6 hv = *(const H6*)(hp + (size_t)s * 32);
            float p = __expf(lrelu((float)hv.a + adn));
            den += p;
#pragma unroll
            for (int c = 0; c < HID; ++c) num[c] = __builtin_fmaf(p, (float)hv.h[c], num[c]);
        }
        float inv = 1.f / den;
#pragma unroll
        for (int c = 0; c < HID; ++c) {
            float v = num[c] * inv + b1[h * HID + c];
            sh[ln * C1 + h * HID + c] = v > 0.f ? v : expm1f(v);
        }
    }
    __syncthreads();
    if (tid < NPB) {
        int nn = blockIdx.x * NPB + tid;
        if (nn < N_NODES) {
            float gg[NC] = {0.f, 0.f, 0.f};
#pragma unroll
            for (int j = 0; j < C1; ++j) {
                float hv = sh[tid * C1 + j];
#pragma unroll
                for (int c = 0; c < NC; ++c) gg[c] += hv * W2[j * NC + c];
            }
            float ssv = 0.f, ddv = 0.f;
#pragma unroll
            for (int c = 0; c < NC; ++c) { ssv += gg[c] * as2[c]; ddv += gg[c] * ad2[c]; }
            n2[nn] = make_float4(ssv, gg[0], gg[1], gg[2]);  // [a2s | g0 g1 g2]
            a2d[nn] = ddv;
        }
    }
}

// ---- Layer 2: per-dst segment softmax (no max-shift), 8-way unrolled ----
__global__ void k_layer2(const int* __restrict__ off, const int* __restrict__ deg,
                         const int* __restrict__ ssrc, const float4* __restrict__ n2,
                         const float* __restrict__ a2d, const float* __restrict__ b2,
                         float* __restrict__ out) {
    int n = blockIdx.x * blockDim.x + threadIdx.x;
    if (n >= N_NODES) return;
    int st = off[n], cnt = deg[n];
    float adn = a2d[n];
    float den = 0.f, num0 = 0.f, num1 = 0.f, num2 = 0.f;
    int i = 0;
    for (; i + 7 < cnt; i += 8) {
        float4 g[8];
#pragma unroll
        for (int u = 0; u < 8; ++u) g[u] = n2[ssrc[st + i + u]];
        float ps = 0.f;
#pragma unroll
        for (int u = 0; u < 8; ++u) {
            float p = __expf(lrelu(g[u].x + adn));
            ps += p;
            num0 = __builtin_fmaf(p, g[u].y, num0);
            num1 = __builtin_fmaf(p, g[u].z, num1);
            num2 = __builtin_fmaf(p, g[u].w, num2);
        }
        den += ps;
    }
    for (; i + 3 < cnt; i += 4) {
        float4 g[4];
#pragma unroll
        for (int u = 0; u < 4; ++u) g[u] = n2[ssrc[st + i + u]];
#pragma unroll
        for (int u = 0; u < 4; ++u) {
            float p = __expf(lrelu(g[u].x + adn));
            den += p;
            num0 = __builtin_fmaf(p, g[u].y, num0);
            num1 = __builtin_fmaf(p, g[u].z, num1);
            num2 = __builtin_fmaf(p, g[u].w, num2);
        }
    }
    for (; i < cnt; ++i) {
        float4 gv = n2[ssrc[st + i]];
        float p = __expf(lrelu(gv.x + adn));
        den += p;
        num0 = __builtin_fmaf(p, gv.y, num0);
        num1 = __builtin_fmaf(p, gv.z, num1);
        num2 = __builtin_fmaf(p, gv.w, num2);
    }
    float inv = 1.f / den;
    float vv[NC] = {num0 * inv + b2[0], num1 * inv + b2[1], num2 * inv + b2[2]};
#pragma unroll
    for (int c = 0; c < NC; ++c) {
        float v = vv[c];
        out[n * NC + c] = (v >= 0.f) ? -log1pf(__expf(-v)) : v - log1pf(__expf(v));
    }
}

extern "C" void kernel_launch(void* const* d_in, const int* in_sizes, int n_in,
                              void* d_out, int out_size, void* d_ws, size_t ws_size,
                              hipStream_t stream) {
    const float* x   = (const float*)d_in[0];
    const int*   ei  = (const int*)d_in[1];
    const float* W1  = (const float*)d_in[2];
    const float* as1 = (const float*)d_in[3];
    const float* ad1 = (const float*)d_in[4];
    const float* b1  = (const float*)d_in[5];
    const float* W2  = (const float*)d_in[6];
    const float* as2 = (const float*)d_in[7];
    const float* ad2 = (const float*)d_in[8];
    const float* b2  = (const float*)d_in[9];
    float* out = (float*)d_out;
    int E = in_sizes[1] / 2;
    int TOT = E + N_NODES;

    int*   iws = (int*)d_ws;
    float* fws = (float*)d_ws;
    // ints (no memset needed: every word written before read; no overlays)
    int* hist = iws;                       // NBH2*NDIG = 524,288
    int* bcnt = iws + 524288;              // 1024
    int* off  = iws + 526336;              // N
    int* deg  = iws + 626336;              // N
    int* pk   = iws + 726336;              // TOT
    int* ssrc = pk + TOT;                  // TOT
    size_t fbase = 726336 + 2 * (size_t)TOT;   // ~7.33M floats
    _Float16* h1p = (_Float16*)(fws + fbase);  // N*32 halfs = N*16 floats
    float*  adst = fws + fbase + 1600000;  // N*5
    float4* n2   = (float4*)(fws + fbase + 2100000); // N float4
    float*  a2d  = fws + fbase + 2500000;  // N  (end fbase+2.6M ~ 39.7 MB)

    dim3 blk(256);
    int NB1 = (N_NODES + 255) / 256;  // 391
    int NG  = (N_NODES + 63) / 64;    // 1563 gemm blocks
    k_gemm_hist<<<dim3(NG + NBH2), dim3(256), 0, stream>>>(
        x, W1, as1, ad1, ei, E, TOT, NG, h1p, adst, hist);
    k_colscan<<<dim3(NDIG), dim3(NBH2), 0, stream>>>(hist, bcnt);
    k_write<<<dim3(NBH2), dim3(HTH2), 0, stream>>>(ei, E, TOT, hist, bcnt, pk);
    k_bgroup<<<dim3(NBUCK), dim3(512), 0, stream>>>(bcnt, pk, off, deg, ssrc);
    k_layer1<<<dim3((N_NODES + NPB - 1) / NPB), dim3(NPB * HEADS), 0, stream>>>(
        off, deg, ssrc, h1p, adst, b1, W2, as2, ad2, n2, a2d);
    k_layer2<<<dim3(NB1), blk, 0, stream>>>(off, deg, ssrc, n2, a2d, b2, out);
}